// Round 1
// baseline (155.917 us; speedup 1.0000x reference)
//
#include <hip/hip_runtime.h>

#define N 1024
#define D 256
#define TI 8

// Prep: per-row L2 normalization of mu_X and exp(log_sigma), written TRANSPOSED
// ([D,N]) into workspace. Transposed layout makes the pair kernel's j-side loads
// coalesced (lane j reads muT[d*N + j]) and i-side loads wave-uniform (s_load).
__global__ __launch_bounds__(256) void prep_kernel(
    const float* __restrict__ muX, const float* __restrict__ ls,
    float* __restrict__ muT, float* __restrict__ sqT) {
  const int i = blockIdx.x;   // row
  const int d = threadIdx.x;  // D == 256 == blockDim.x
  const float v = muX[i * D + d];
  __shared__ float sred[256];
  sred[d] = v * v;
  __syncthreads();
  for (int s = 128; s > 0; s >>= 1) {
    if (d < s) sred[d] += sred[d + s];
    __syncthreads();
  }
  const float norm = sqrtf(sred[0]);
  const float denom = fmaxf(norm, 1e-12f);  // F.normalize eps semantics
  muT[d * N + i] = v / denom;
  sqT[d * N + i] = __expf(ls[i * D + d]);
}

// Pair kernel: thread <-> output column j; each block covers TI=8 rows.
// acc[i,j] = sum_d (mu_i-mu_j)^2 / (1e-10 + s_i + s_j) + ln(s_i + s_j)
// i-side values are wave-uniform -> scalar loads (8 contiguous floats ->
// s_load_dwordx8); j-side values are coalesced vector loads (L2-resident, 2 MB).
__global__ __launch_bounds__(256) void pair_kernel(
    const float* __restrict__ muT, const float* __restrict__ sqT,
    float* __restrict__ out) {
  const int j = blockIdx.x * 256 + threadIdx.x;
  const int i0 = blockIdx.y * TI;
  float acc[TI];
#pragma unroll
  for (int k = 0; k < TI; ++k) acc[k] = 0.f;
  constexpr float LN2 = 0.6931471805599453f;
#pragma unroll 4
  for (int d = 0; d < D; ++d) {
    const float mj = muT[d * N + j];
    const float sj = sqT[d * N + j];
#pragma unroll
    for (int k = 0; k < TI; ++k) {
      const float mi = muT[d * N + i0 + k];  // uniform -> SGPR
      const float si = sqT[d * N + i0 + k];  // uniform -> SGPR
      const float t = mi - mj;
      const float s = si + sj;
      const float r = __builtin_amdgcn_rcpf(s + 1e-10f);  // v_rcp_f32
      const float lg = __log2f(s);                        // v_log_f32
      acc[k] = fmaf(t * t, r, acc[k]);
      acc[k] = fmaf(lg, LN2, acc[k]);
    }
  }
#pragma unroll
  for (int k = 0; k < TI; ++k) out[(size_t)(i0 + k) * N + j] = -acc[k];
}

extern "C" void kernel_launch(void* const* d_in, const int* in_sizes, int n_in,
                              void* d_out, int out_size, void* d_ws, size_t ws_size,
                              hipStream_t stream) {
  const float* muX = (const float*)d_in[0];
  const float* ls  = (const float*)d_in[1];
  float* out = (float*)d_out;
  float* muT = (float*)d_ws;                 // [D, N]
  float* sqT = muT + (size_t)N * D;          // [D, N]  (2 MB total scratch)
  prep_kernel<<<dim3(N), dim3(256), 0, stream>>>(muX, ls, muT, sqT);
  pair_kernel<<<dim3(N / 256, N / TI), dim3(256), 0, stream>>>(muT, sqT, out);
}

// Round 2
// 149.023 us; speedup vs baseline: 1.0463x; 1.0463x over previous
//
#include <hip/hip_runtime.h>

#define N 1024
#define D 256

// Prep: per-row L2-normalize mu_X, sigsq = exp(log_sigma) + 5e-11 (eps folded so
// si'+sj' = sig_sum + 1e-10), written interleaved AND transposed: msT[d*N + i] =
// {mu, sigsq}. Transposed layout -> pair kernel's j-side loads coalesced.
__global__ __launch_bounds__(256) void prep_kernel(
    const float* __restrict__ muX, const float* __restrict__ ls,
    float2* __restrict__ msT) {
  const int i = blockIdx.x;   // row
  const int d = threadIdx.x;  // D == 256 == blockDim.x
  const float v = muX[i * D + d];
  __shared__ float sred[256];
  sred[d] = v * v;
  __syncthreads();
  for (int s = 128; s > 0; s >>= 1) {
    if (d < s) sred[d] += sred[d + s];
    __syncthreads();
  }
  const float denom = fmaxf(sqrtf(sred[0]), 1e-12f);  // F.normalize eps
  float2 ms;
  ms.x = v / denom;
  ms.y = __expf(ls[i * D + d]) + 5e-11f;
  msT[(size_t)d * N + i] = ms;
}

// Pair kernel, symmetric: only upper-triangular 16x16 tiles (2080 blocks of 1
// wave). Per element-d: s=si+sj, t=mi-mj, r=rcp(s), accA=fma(t*t,r,accA),
// p*=s  -> 5 full-rate + 1 quarter-rate op. log(s) recovered from the product's
// exponent (extracted every 4 d's) + one __log2f at the end.
__global__ __launch_bounds__(64) void pair_kernel(
    const float2* __restrict__ msT, float* __restrict__ out) {
  // decode linear block id -> (bi <= bj) triangular tile coords
  const int l = blockIdx.x;
  int b = (int)((sqrtf(8.f * (float)l + 1.f) - 1.f) * 0.5f);
  while (b * (b + 1) / 2 > l) --b;
  while ((b + 1) * (b + 2) / 2 <= l) ++b;
  const int bi = l - b * (b + 1) / 2;  // row tile index (<= bj)
  const int bj = b;                    // col tile index
  const int i0 = bi * 16, j0 = bj * 16;

  const int t = threadIdx.x;
  const int c = t & 15;   // col within tile
  const int rg = t >> 4;  // 0..3 row group; rows rg + 4m, m=0..3

  const float2* __restrict__ pj = msT + j0 + c;
  const float2* __restrict__ pi = msT + i0 + rg;

  float accA[4] = {0.f, 0.f, 0.f, 0.f};
  float p[4] = {1.f, 1.f, 1.f, 1.f};
  int ea[4] = {0, 0, 0, 0};

  for (int g = 0; g < D / 4; ++g) {
#pragma unroll
    for (int u = 0; u < 4; ++u) {
      const float2 j2 = pj[(size_t)u * N];
#pragma unroll
      for (int m = 0; m < 4; ++m) {
        const float2 i2 = pi[(size_t)u * N + 4 * m];
        const float s = i2.y + j2.y;          // sig_sum + 1e-10
        const float d0 = i2.x - j2.x;
        const float r = __builtin_amdgcn_rcpf(s);
        accA[m] = fmaf(d0 * d0, r, accA[m]);
        p[m] *= s;                            // log via product
      }
    }
    pj += (size_t)4 * N;
    pi += (size_t)4 * N;
    // renormalize: strip exponent into ea, mantissa back to [1,2)
#pragma unroll
    for (int m = 0; m < 4; ++m) {
      const int bb = __float_as_int(p[m]);
      ea[m] += (bb >> 23);
      p[m] = __int_as_float((bb & 0x007fffff) | 0x3f800000);
    }
  }

  constexpr float LN2 = 0.6931471805599453f;
  float vals[4];
#pragma unroll
  for (int m = 0; m < 4; ++m) {
    const float lg2 = (float)(ea[m] - 127 * (D / 4)) + __log2f(p[m]);
    vals[m] = -(accA[m] + LN2 * lg2);
  }

  // direct (upper) write: coalesced
#pragma unroll
  for (int m = 0; m < 4; ++m)
    out[(size_t)(i0 + rg + 4 * m) * N + (j0 + c)] = vals[m];

  // mirror (lower) write via LDS transpose; skip on diagonal tiles
  __shared__ float tile[16 * 17];
  if (bi != bj) {
#pragma unroll
    for (int m = 0; m < 4; ++m) tile[(rg + 4 * m) * 17 + c] = vals[m];
    __syncthreads();
#pragma unroll
    for (int m = 0; m < 4; ++m) {
      const float v = tile[c * 17 + (rg + 4 * m)];
      out[(size_t)(j0 + rg + 4 * m) * N + (i0 + c)] = v;
    }
  }
}

extern "C" void kernel_launch(void* const* d_in, const int* in_sizes, int n_in,
                              void* d_out, int out_size, void* d_ws, size_t ws_size,
                              hipStream_t stream) {
  const float* muX = (const float*)d_in[0];
  const float* ls  = (const float*)d_in[1];
  float* out = (float*)d_out;
  float2* msT = (float2*)d_ws;  // [D, N] interleaved {mu, sigsq} = 2 MB
  prep_kernel<<<dim3(N), dim3(256), 0, stream>>>(muX, ls, msT);
  const int ntiles = (N / 16) * (N / 16 + 1) / 2;  // 2080
  pair_kernel<<<dim3(ntiles), dim3(64), 0, stream>>>(msT, out);
}

// Round 3
// 106.933 us; speedup vs baseline: 1.4581x; 1.3936x over previous
//
#include <hip/hip_runtime.h>

#define N 1024
#define D 256
#define RI 32

// Prep: 32 rows/block, tiled transpose. Phase 1: row L2-norms (8 lanes/row).
// Phase 2: write msT4[g][i] = (mu_2g, sig_2g, mu_2g+1, sig_2g+1), g = d/2,
// as per-lane float2 halves -> 512B contiguous per wave (coalesced; fixes the
// R2 prep whose stores scattered 64 lanes across 64 cache lines).
__global__ __launch_bounds__(256) void prep2(
    const float* __restrict__ muX, const float* __restrict__ ls,
    float4* __restrict__ msT4) {
  const int i0 = blockIdx.x * RI;
  const int t = threadIdx.x;
  __shared__ float sred[RI][8];
  __shared__ float rden[RI];
  const int r = t >> 3, q = t & 7;
  const float4* rowp = (const float4*)(muX + (size_t)(i0 + r) * D);
  float s = 0.f;
#pragma unroll
  for (int k = 0; k < 8; ++k) {
    const float4 v = rowp[q + 8 * k];
    s += v.x * v.x + v.y * v.y + v.z * v.z + v.w * v.w;
  }
  sred[r][q] = s;
  __syncthreads();
  if (q == 0) {
    float tot = 0.f;
    for (int u = 0; u < 8; ++u) tot += sred[r][u];
    rden[r] = 1.0f / fmaxf(sqrtf(tot), 1e-12f);  // F.normalize eps
  }
  __syncthreads();
  const int w = t >> 6, l = t & 63;
  const int il = l >> 1, b = l & 1;  // lane -> (column, float2 half)
  const float rd = rden[il];
  const int row = i0 + il;
  float2* outp = (float2*)msT4;
  for (int it = 0; it < 32; ++it) {
    const int g = it * 4 + w;
    const int d = 2 * g + b;
    const float mu = muX[(size_t)row * D + d] * rd;
    const float sg = __expf(ls[(size_t)row * D + d]) + 5e-11f;  // eps folded
    outp[((size_t)g * N + row) * 2 + b] = make_float2(mu, sg);
  }
}

// Pair kernel: triangular tiles of 4 rows x 128 cols, 1152 blocks x 2 waves.
// i-side indices are wave-uniform -> scalar loads (s_load_dwordx16 per g);
// j-side is one coalesced float4 (2 d's) per lane. Per element: 5 full-rate
// VALU + 1 rcp; ln via running product + exponent extraction (one __log2f
// per output).
__global__ __launch_bounds__(128) void pair_kernel(
    const float4* __restrict__ msT4, float* __restrict__ out) {
  int L = blockIdx.x;
  int js = 0, base = 0;  // slab js has 32*(js+1) row-tiles
  while (L >= base + 32 * (js + 1)) { base += 32 * (js + 1); ++js; }
  const int ib = L - base;
  const int j0 = js * 128, i0 = ib * 4;
  const bool diag = (ib >= js * 32);  // tile straddles the diagonal
  const int j = j0 + threadIdx.x;

  float acc[4] = {0.f, 0.f, 0.f, 0.f};
  float p[4] = {1.f, 1.f, 1.f, 1.f};
  int ea[4] = {0, 0, 0, 0};

#pragma unroll 4
  for (int g = 0; g < D / 2; ++g) {
    const float4 jv = msT4[(size_t)g * N + j];
#pragma unroll
    for (int k = 0; k < 4; ++k) {
      const float4 iv = msT4[(size_t)g * N + i0 + k];  // uniform -> SGPR
      {
        const float sv = iv.y + jv.y;
        const float t0 = iv.x - jv.x;
        acc[k] = fmaf(t0 * t0, __builtin_amdgcn_rcpf(sv), acc[k]);
        p[k] *= sv;
      }
      {
        const float sv = iv.w + jv.w;
        const float t0 = iv.z - jv.z;
        acc[k] = fmaf(t0 * t0, __builtin_amdgcn_rcpf(sv), acc[k]);
        p[k] *= sv;
      }
    }
    if (g & 1) {  // renorm every 4 d's: |log2 s|<~9 -> p in 2^+-36, safe
#pragma unroll
      for (int k = 0; k < 4; ++k) {
        const int bb = __float_as_int(p[k]);
        ea[k] += bb >> 23;
        p[k] = __int_as_float((bb & 0x007fffff) | 0x3f800000);
      }
    }
  }

  constexpr float LN2 = 0.6931471805599453f;
  float v[4];
#pragma unroll
  for (int k = 0; k < 4; ++k) {
    const float lg2 = (float)(ea[k] - 127 * (D / 4)) + __log2f(p[k]);
    v[k] = -(acc[k] + LN2 * lg2);
  }

  if (!diag) {  // strictly-upper tile: unmasked direct + mirror writes
#pragma unroll
    for (int k = 0; k < 4; ++k) out[(size_t)(i0 + k) * N + j] = v[k];
    float4 m;
    m.x = v[0]; m.y = v[1]; m.z = v[2]; m.w = v[3];
    *(float4*)(out + (size_t)j * N + i0) = m;  // 16B/lane transpose write
  } else {      // diagonal tile: per-element masks (j>=i direct, j>i mirror)
#pragma unroll
    for (int k = 0; k < 4; ++k) {
      const int i = i0 + k;
      if (j >= i) out[(size_t)i * N + j] = v[k];
      if (j > i) out[(size_t)j * N + i] = v[k];
    }
  }
}

extern "C" void kernel_launch(void* const* d_in, const int* in_sizes, int n_in,
                              void* d_out, int out_size, void* d_ws, size_t ws_size,
                              hipStream_t stream) {
  const float* muX = (const float*)d_in[0];
  const float* ls  = (const float*)d_in[1];
  float* out = (float*)d_out;
  float4* msT4 = (float4*)d_ws;  // [D/2][N] packed (mu,sig) pairs = 2 MB
  prep2<<<dim3(N / RI), dim3(256), 0, stream>>>(muX, ls, msT4);
  pair_kernel<<<dim3(1152), dim3(128), 0, stream>>>(msT4, out);
}

// Round 4
// 100.139 us; speedup vs baseline: 1.5570x; 1.0678x over previous
//
#include <hip/hip_runtime.h>

#define N 1024
#define D 256

// ---------------- prep ----------------
// 128 blocks x 8 rows, LDS-staged: coalesced float4 global loads, padded-LDS
// transpose, coalesced 8B stores (128B runs). Replaces R3's 32-block prep2
// whose scattered per-row scalar loads were latency-bound.
#define RI 8
#define LDW 260  // padded LDS row stride: %4==0 (float4 stores ok), +4 banks/row

__global__ __launch_bounds__(256) void prep3(
    const float* __restrict__ muX, const float* __restrict__ ls,
    float2* __restrict__ msT2) {
  const int i0 = blockIdx.x * RI;
  const int t = threadIdx.x;
  __shared__ float smu[RI][LDW];
  __shared__ float ssg[RI][LDW];
  __shared__ float sred[RI][32];
  __shared__ float rden[RI];
  const float4* mu4 = (const float4*)(muX + (size_t)i0 * D);
  const float4* ls4 = (const float4*)(ls + (size_t)i0 * D);
#pragma unroll
  for (int u = 0; u < 2; ++u) {
    const int idx = u * 256 + t;  // float4 index within the 8x256 row block
    const int row = idx >> 6, c4 = idx & 63;
    const float4 v = mu4[idx];
    *(float4*)&smu[row][c4 * 4] = v;
    const float4 e = ls4[idx];
    float4 x;
    x.x = __expf(e.x) + 5e-11f; x.y = __expf(e.y) + 5e-11f;  // eps folded
    x.z = __expf(e.z) + 5e-11f; x.w = __expf(e.w) + 5e-11f;
    *(float4*)&ssg[row][c4 * 4] = x;
  }
  __syncthreads();
  {
    const int r = t >> 5, q = t & 31;  // 32 lanes per row
    float s = 0.f;
#pragma unroll
    for (int k = 0; k < 8; ++k) {
      const float v = smu[r][q + 32 * k];
      s = fmaf(v, v, s);
    }
    sred[r][q] = s;
  }
  __syncthreads();
  if (t < RI) {
    float tot = 0.f;
    for (int u = 0; u < 32; ++u) tot += sred[t][u];
    rden[t] = 1.0f / fmaxf(sqrtf(tot), 1e-12f);  // F.normalize eps
  }
  __syncthreads();
#pragma unroll
  for (int pass = 0; pass < 8; ++pass) {
    const int f = pass * 256 + t;
    const int b = f & 1, il = (f >> 1) & 7, g = f >> 4;
    const int d = 2 * g + b;
    msT2[((size_t)g * N + i0 + il) * 2 + b] =
        make_float2(smu[il][d] * rden[il], ssg[il][d]);
  }
}

// ---------------- pair ----------------
// Triangular 4x128 tiles (1152 blocks x 2 waves), i-side wave-uniform (SGPR),
// j-side coalesced float4. NEW: depth-2 software pipeline — prefetch g+2/g+3
// (j in VGPRs, i in SGPRs) while computing g/g+1, so L2 latency overlaps 288cy
// of VALU work instead of serializing per iteration (R3 duty was ~19%).
#define UPD(jv, iv, k)                                           \
  {                                                              \
    const float s0 = (iv).y + (jv).y;                            \
    const float t0 = (iv).x - (jv).x;                            \
    acc[k] = fmaf(t0 * t0, __builtin_amdgcn_rcpf(s0), acc[k]);   \
    p[k] *= s0;                                                  \
    const float s1 = (iv).w + (jv).w;                            \
    const float t1 = (iv).z - (jv).z;                            \
    acc[k] = fmaf(t1 * t1, __builtin_amdgcn_rcpf(s1), acc[k]);   \
    p[k] *= s1;                                                  \
  }

__global__ __launch_bounds__(128) void pair_kernel(
    const float4* __restrict__ msT4, float* __restrict__ out) {
  int L = blockIdx.x;
  int js = 0, base = 0;  // slab js has 32*(js+1) row-tiles
  while (L >= base + 32 * (js + 1)) { base += 32 * (js + 1); ++js; }
  const int ib = L - base;
  const int j0 = js * 128, i0 = ib * 4;
  const bool diag = (ib >= js * 32);
  const int j = j0 + threadIdx.x;

  const float4* __restrict__ pj = msT4 + j;
  const float4* __restrict__ pi = msT4 + i0;

  float acc[4] = {0.f, 0.f, 0.f, 0.f};
  float p[4] = {1.f, 1.f, 1.f, 1.f};
  int ea[4] = {0, 0, 0, 0};

  float4 jA = pj[0];
  float4 jB = pj[(size_t)N];
  float4 iA0 = pi[0], iA1 = pi[1], iA2 = pi[2], iA3 = pi[3];
  float4 iB0 = pi[N + 0], iB1 = pi[N + 1], iB2 = pi[N + 2], iB3 = pi[N + 3];

  for (int g = 0; g < D / 2; g += 2) {
    const size_t o2 = (size_t)((g + 2 < D / 2) ? g + 2 : 0) * N;  // clamped
    const size_t o3 = (size_t)((g + 3 < D / 2) ? g + 3 : 0) * N;
    const float4 njA = pj[o2];
    const float4 niA0 = pi[o2 + 0], niA1 = pi[o2 + 1];
    const float4 niA2 = pi[o2 + 2], niA3 = pi[o2 + 3];
    const float4 njB = pj[o3];
    const float4 niB0 = pi[o3 + 0], niB1 = pi[o3 + 1];
    const float4 niB2 = pi[o3 + 2], niB3 = pi[o3 + 3];

    UPD(jA, iA0, 0) UPD(jA, iA1, 1) UPD(jA, iA2, 2) UPD(jA, iA3, 3)
    UPD(jB, iB0, 0) UPD(jB, iB1, 1) UPD(jB, iB2, 2) UPD(jB, iB3, 3)

    // renorm every 4 d's: |log2 s| <= ~14 -> product exponent stays in range
#pragma unroll
    for (int k = 0; k < 4; ++k) {
      const int bb = __float_as_int(p[k]);
      ea[k] += bb >> 23;
      p[k] = __int_as_float((bb & 0x007fffff) | 0x3f800000);
    }

    jA = njA; jB = njB;
    iA0 = niA0; iA1 = niA1; iA2 = niA2; iA3 = niA3;
    iB0 = niB0; iB1 = niB1; iB2 = niB2; iB3 = niB3;
  }

  constexpr float LN2 = 0.6931471805599453f;
  float v[4];
#pragma unroll
  for (int k = 0; k < 4; ++k) {
    const float lg2 = (float)(ea[k] - 127 * (D / 4)) + __log2f(p[k]);
    v[k] = -(acc[k] + LN2 * lg2);
  }

  if (!diag) {  // strictly-upper tile: unmasked direct + mirror writes
#pragma unroll
    for (int k = 0; k < 4; ++k) out[(size_t)(i0 + k) * N + j] = v[k];
    float4 m;
    m.x = v[0]; m.y = v[1]; m.z = v[2]; m.w = v[3];
    *(float4*)(out + (size_t)j * N + i0) = m;  // 16B/lane transpose write
  } else {  // diagonal tile: per-element masks
#pragma unroll
    for (int k = 0; k < 4; ++k) {
      const int i = i0 + k;
      if (j >= i) out[(size_t)i * N + j] = v[k];
      if (j > i) out[(size_t)j * N + i] = v[k];
    }
  }
}

extern "C" void kernel_launch(void* const* d_in, const int* in_sizes, int n_in,
                              void* d_out, int out_size, void* d_ws, size_t ws_size,
                              hipStream_t stream) {
  const float* muX = (const float*)d_in[0];
  const float* ls  = (const float*)d_in[1];
  float* out = (float*)d_out;
  float2* msT2 = (float2*)d_ws;  // [D/2][N][2] packed (mu,sig) pairs = 2 MB
  prep3<<<dim3(N / RI), dim3(256), 0, stream>>>(muX, ls, msT2);
  pair_kernel<<<dim3(1152), dim3(128), 0, stream>>>((const float4*)msT2,
                                                    out);
}

// Round 5
// 95.919 us; speedup vs baseline: 1.6255x; 1.0440x over previous
//
#include <hip/hip_runtime.h>

#define N 1024
#define D 256

// ---------------- prep ----------------
// 128 blocks x 8 rows, LDS-staged: coalesced float4 global loads, padded-LDS
// transpose, coalesced 8B stores (128B runs).
#define RI 8
#define LDW 260  // padded LDS row stride: %4==0 (float4 stores ok), +4 banks/row

__global__ __launch_bounds__(256) void prep3(
    const float* __restrict__ muX, const float* __restrict__ ls,
    float2* __restrict__ msT2) {
  const int i0 = blockIdx.x * RI;
  const int t = threadIdx.x;
  __shared__ float smu[RI][LDW];
  __shared__ float ssg[RI][LDW];
  __shared__ float sred[RI][32];
  __shared__ float rden[RI];
  const float4* mu4 = (const float4*)(muX + (size_t)i0 * D);
  const float4* ls4 = (const float4*)(ls + (size_t)i0 * D);
#pragma unroll
  for (int u = 0; u < 2; ++u) {
    const int idx = u * 256 + t;  // float4 index within the 8x256 row block
    const int row = idx >> 6, c4 = idx & 63;
    const float4 v = mu4[idx];
    *(float4*)&smu[row][c4 * 4] = v;
    const float4 e = ls4[idx];
    float4 x;
    x.x = __expf(e.x) + 5e-11f; x.y = __expf(e.y) + 5e-11f;  // eps folded
    x.z = __expf(e.z) + 5e-11f; x.w = __expf(e.w) + 5e-11f;
    *(float4*)&ssg[row][c4 * 4] = x;
  }
  __syncthreads();
  {
    const int r = t >> 5, q = t & 31;  // 32 lanes per row
    float s = 0.f;
#pragma unroll
    for (int k = 0; k < 8; ++k) {
      const float v = smu[r][q + 32 * k];
      s = fmaf(v, v, s);
    }
    sred[r][q] = s;
  }
  __syncthreads();
  if (t < RI) {
    float tot = 0.f;
    for (int u = 0; u < 32; ++u) tot += sred[t][u];
    rden[t] = 1.0f / fmaxf(sqrtf(tot), 1e-12f);  // F.normalize eps
  }
  __syncthreads();
#pragma unroll
  for (int pass = 0; pass < 8; ++pass) {
    const int f = pass * 256 + t;
    const int b = f & 1, il = (f >> 1) & 7, g = f >> 4;
    const int d = 2 * g + b;
    msT2[((size_t)g * N + i0 + il) * 2 + b] =
        make_float2(smu[il][d] * rden[il], ssg[il][d]);
  }
}

// ---------------- pair ----------------
// Triangular 2x128 tiles: 2304 blocks x 2 waves = 4608 waves = 4.5/SIMD
// (R4 had only 2.25/SIMD; per-wave duty ~20% vs L2 latency capped VALUBusy
// at 43% — TLP is the lever, not ILP). i-side wave-uniform (SGPR), j-side
// coalesced float4. ln via running product + exponent strip every 4 d's.
__global__ __launch_bounds__(128) void pair_kernel(
    const float4* __restrict__ msT4, float* __restrict__ out) {
  int L = blockIdx.x;
  int js = 0, base = 0;  // slab js has 64*(js+1) row-tiles of 2 rows
  while (L >= base + 64 * (js + 1)) { base += 64 * (js + 1); ++js; }
  const int ib = L - base;
  const int j0 = js * 128, i0 = ib * 2;
  const bool diag = (ib >= js * 64);  // tile straddles the diagonal
  const int j = j0 + threadIdx.x;

  float acc[2] = {0.f, 0.f};
  float p[2] = {1.f, 1.f};
  int ea[2] = {0, 0};

#pragma unroll 4
  for (int g = 0; g < D / 2; ++g) {
    const float4 jv = msT4[(size_t)g * N + j];
#pragma unroll
    for (int k = 0; k < 2; ++k) {
      const float4 iv = msT4[(size_t)g * N + i0 + k];  // uniform -> SGPR
      {
        const float sv = iv.y + jv.y;
        const float t0 = iv.x - jv.x;
        acc[k] = fmaf(t0 * t0, __builtin_amdgcn_rcpf(sv), acc[k]);
        p[k] *= sv;
      }
      {
        const float sv = iv.w + jv.w;
        const float t0 = iv.z - jv.z;
        acc[k] = fmaf(t0 * t0, __builtin_amdgcn_rcpf(sv), acc[k]);
        p[k] *= sv;
      }
    }
    if (g & 1) {  // renorm every 4 d's: |log2 s| <= ~8 -> exponent safe
#pragma unroll
      for (int k = 0; k < 2; ++k) {
        const int bb = __float_as_int(p[k]);
        ea[k] += bb >> 23;
        p[k] = __int_as_float((bb & 0x007fffff) | 0x3f800000);
      }
    }
  }

  constexpr float LN2 = 0.6931471805599453f;
  float v[2];
#pragma unroll
  for (int k = 0; k < 2; ++k) {
    const float lg2 = (float)(ea[k] - 127 * (D / 4)) + __log2f(p[k]);
    v[k] = -(acc[k] + LN2 * lg2);
  }

  if (!diag) {  // strictly-upper tile: unmasked direct + mirror writes
    out[(size_t)i0 * N + j] = v[0];
    out[(size_t)(i0 + 1) * N + j] = v[1];
    *(float2*)(out + (size_t)j * N + i0) = make_float2(v[0], v[1]);
  } else {  // diagonal tile: per-element masks
#pragma unroll
    for (int k = 0; k < 2; ++k) {
      const int i = i0 + k;
      if (j >= i) out[(size_t)i * N + j] = v[k];
      if (j > i) out[(size_t)j * N + i] = v[k];
    }
  }
}

extern "C" void kernel_launch(void* const* d_in, const int* in_sizes, int n_in,
                              void* d_out, int out_size, void* d_ws, size_t ws_size,
                              hipStream_t stream) {
  const float* muX = (const float*)d_in[0];
  const float* ls  = (const float*)d_in[1];
  float* out = (float*)d_out;
  float2* msT2 = (float2*)d_ws;  // [D/2][N][2] packed (mu,sig) pairs = 2 MB
  prep3<<<dim3(N / RI), dim3(256), 0, stream>>>(muX, ls, msT2);
  const int nblocks = 64 * (8 * 9 / 2);  // 2304 triangular 2x128 tiles
  pair_kernel<<<dim3(nblocks), dim3(128), 0, stream>>>((const float4*)msT2,
                                                       out);
}